// Round 4
// baseline (137.310 us; speedup 1.0000x reference)
//
#include <hip/hip_runtime.h>
#include <math.h>
#include <limits.h>

namespace {

constexpr int B_ = 16;
constexpr int H_ = 512;
constexpr int W_ = 512;
constexpr int HW_ = H_ * W_;
constexpr int TS_ = 32;
constexpr int CAP_ = 4096;   // one slot per 8x8 sub-block per image (64*64)
constexpr int NSEL_ = 500;

// 7-tap gaussian, sigma=1, normalized (matches reference's np.exp/sum)
__device__ __constant__ float c_gw[7] = {
    0.004433048175243746f, 0.05400558262251428f, 0.24203622937611957f,
    0.3990502796522496f,  0.24203622937611957f, 0.05400558262251428f,
    0.004433048175243746f};

__device__ inline int reflect_i(int i, int n) {
  // jnp.pad mode='reflect': -1 -> 1, n -> n-2
  return i < 0 ? -i : (i > n - 1 ? 2 * (n - 1) - i : i);
}

// K1: imgs -> GFTT response map. One block = one 32x32 output tile.
__global__ __launch_bounds__(256) void k_resp(const float* __restrict__ imgs,
                                              float* __restrict__ resp) {
  int bid = blockIdx.x;
  int bx = bid & 15, by = (bid >> 4) & 15, b = bid >> 8;
  int r0 = by * TS_, c0 = bx * TS_;
  __shared__ float g_s[40][40];
  __shared__ float p_s[3][38][38];
  __shared__ float v_s[3][TS_][38];
  int tid = threadIdx.x;
  const float* img = imgs + (size_t)b * 3 * HW_;

  // grayscale with replicate clamp (matches sobel's edge padding)
  for (int l = tid; l < 40 * 40; l += 256) {
    int lr = l / 40, lc = l % 40;
    int gr = min(max(r0 - 4 + lr, 0), H_ - 1);
    int gc = min(max(c0 - 4 + lc, 0), W_ - 1);
    int o = gr * W_ + gc;
    g_s[lr][lc] = 0.299f * img[o] + 0.587f * img[HW_ + o] + 0.114f * img[2 * HW_ + o];
  }
  __syncthreads();

  // gradient products at rows/cols tile-3 .. tile+34, reflect-mapped into image
  for (int l = tid; l < 38 * 38; l += 256) {
    int lr = l / 38, lc = l % 38;
    int ar = reflect_i(r0 - 3 + lr, H_);
    int ac = reflect_i(c0 - 3 + lc, W_);
    int rm = max(ar - 1, 0)      - (r0 - 4);
    int rz = ar                  - (r0 - 4);
    int rp = min(ar + 1, H_ - 1) - (r0 - 4);
    int cm = max(ac - 1, 0)      - (c0 - 4);
    int cz = ac                  - (c0 - 4);
    int cp = min(ac + 1, W_ - 1) - (c0 - 4);
    float gnw = g_s[rm][cm], gn = g_s[rm][cz], gne = g_s[rm][cp];
    float gw_ = g_s[rz][cm],                   ge  = g_s[rz][cp];
    float gsw = g_s[rp][cm], gs = g_s[rp][cz], gse = g_s[rp][cp];
    float dx = ((gne - gnw) + 2.f * (ge - gw_) + (gse - gsw)) * 0.125f;
    float dy = ((gsw - gnw) + 2.f * (gs - gn) + (gse - gne)) * 0.125f;
    p_s[0][lr][lc] = dx * dx;
    p_s[1][lr][lc] = dy * dy;
    p_s[2][lr][lc] = dx * dy;
  }
  __syncthreads();

  // vertical 7-tap blur
  for (int l = tid; l < TS_ * 38; l += 256) {
    int lr = l / 38, lc = l % 38;
    float s0 = 0.f, s1 = 0.f, s2 = 0.f;
#pragma unroll
    for (int k = 0; k < 7; k++) {
      float w = c_gw[k];
      s0 += w * p_s[0][lr + k][lc];
      s1 += w * p_s[1][lr + k][lc];
      s2 += w * p_s[2][lr + k][lc];
    }
    v_s[0][lr][lc] = s0;
    v_s[1][lr][lc] = s1;
    v_s[2][lr][lc] = s2;
  }
  __syncthreads();

  // horizontal blur + min-eigenvalue response
  for (int l = tid; l < TS_ * TS_; l += 256) {
    int lr = l / TS_, lc = l % TS_;
    float b0 = 0.f, b1 = 0.f, b2 = 0.f;
#pragma unroll
    for (int k = 0; k < 7; k++) {
      float w = c_gw[k];
      b0 += w * v_s[0][lr][lc + k];
      b1 += w * v_s[1][lr][lc + k];
      b2 += w * v_s[2][lr][lc + k];
    }
    float tr = b0 + b1;
    float det = b0 * b1 - b2 * b2;
    float r = 0.5f * (tr - sqrtf(fabsf(tr * tr - 4.f * det) + 1e-12f));
    resp[((size_t)b * H_ + (r0 + lr)) * W_ + (c0 + lc)] = r;
  }
}

// K2: 5x5 NMS (pad=-inf) + per-8x8-block max into DETERMINISTIC slot
// cand[b*4096 + sub_global]. No atomics. Tie-break: min flat index.
__global__ __launch_bounds__(256) void k_nms(const float* __restrict__ resp,
                                             float* __restrict__ cand_val,
                                             int* __restrict__ cand_idx) {
  int bid = blockIdx.x;
  int bx = bid & 15, by = (bid >> 4) & 15, b = bid >> 8;
  int r0 = by * TS_, c0 = bx * TS_;
  __shared__ float r_s[36][36];
  __shared__ float c_s[32][32];
  int tid = threadIdx.x;
  const float* rb = resp + (size_t)b * HW_;
  for (int l = tid; l < 36 * 36; l += 256) {
    int lr = l / 36, lc = l % 36;
    int gr = r0 - 2 + lr, gc = c0 - 2 + lc;
    float v = -INFINITY;
    if (gr >= 0 && gr < H_ && gc >= 0 && gc < W_) v = rb[gr * W_ + gc];
    r_s[lr][lc] = v;
  }
  __syncthreads();
  for (int l = tid; l < 1024; l += 256) {
    int lr = l >> 5, lc = l & 31;
    float v = r_s[lr + 2][lc + 2];
    float m = -INFINITY;
#pragma unroll
    for (int u = 0; u < 5; u++)
#pragma unroll
      for (int w = 0; w < 5; w++) m = fmaxf(m, r_s[lr + u][lc + w]);
    c_s[lr][lc] = (v == m) ? v : 0.f;
  }
  __syncthreads();
  // one thread per 8x8 sub-block: max + min-index argmax, direct slot write
  if (tid < 16) {
    int sr = (tid >> 2) << 3, sc = (tid & 3) << 3;
    float m = 0.f;
    int mi = INT_MAX;
#pragma unroll
    for (int u = 0; u < 8; u++)
      for (int w = 0; w < 8; w++) {
        float v = c_s[sr + u][sc + w];
        if (v > m) { m = v; mi = (r0 + sr + u) * W_ + (c0 + sc + w); }
      }
    int subg = ((r0 + sr) >> 3) * 64 + ((c0 + sc) >> 3);
    bool pos = (m > 0.f);
    cand_val[b * CAP_ + subg] = pos ? m : -INFINITY;
    cand_idx[b * CAP_ + subg] = pos ? mi : INT_MAX;
  }
}

// K3: per-image top-500 via MSB-first RADIX SELECT (no sort). Items live in
// registers (4/thread). 4 passes x 8 bits: LDS histogram + serial scan find
// the 500th-largest key T and `need` = slots left for key==T (idx asc, ==
// jax.lax.top_k tie order). Second nms2d is a provable no-op (equal values
// survive x==maxpool), so every selected positive item is a corner: add its
// BCE swap term (log p - log1p(-p)) directly.
__global__ __launch_bounds__(1024) void k_select(const float* __restrict__ cand_val,
                                                 const int* __restrict__ cand_idx,
                                                 const float* __restrict__ scores,
                                                 double* __restrict__ acc) {
  int b = blockIdx.x;
  __shared__ unsigned hist[256];
  __shared__ unsigned s_prefix;
  __shared__ int s_rank;
  __shared__ int eq_idx[1024];
  __shared__ int eq_cnt;
  __shared__ float wsum[16];
  int tid = threadIdx.x;

  unsigned key[4];
  int idx[4];
#pragma unroll
  for (int q = 0; q < 4; q++) {
    int l = tid + q * 1024;
    float v = cand_val[b * CAP_ + l];
    idx[q] = cand_idx[b * CAP_ + l];
    unsigned u = __float_as_uint(v);
    key[q] = (u & 0x80000000u) ? ~u : (u | 0x80000000u);  // order-preserving
  }
  if (tid == 0) { s_rank = NSEL_; s_prefix = 0; eq_cnt = 0; }

  for (int pass = 0; pass < 4; pass++) {
    int shift = 24 - 8 * pass;
    if (tid < 256) hist[tid] = 0;
    __syncthreads();
    unsigned pref = s_prefix;
#pragma unroll
    for (int q = 0; q < 4; q++) {
      bool match = (pass == 0) || ((key[q] >> (shift + 8)) == pref);
      if (match) atomicAdd(&hist[(key[q] >> shift) & 255u], 1u);
    }
    __syncthreads();
    if (tid == 0) {
      int rank = s_rank;
      unsigned cum = 0;
      for (int bb = 255; bb >= 0; bb--) {
        unsigned h = hist[bb];
        if (cum + h >= (unsigned)rank) {
          s_rank = rank - (int)cum;
          s_prefix = (pref << 8) | (unsigned)bb;
          break;
        }
        cum += h;
      }
    }
    __syncthreads();
  }
  unsigned T = s_prefix;
  int need = s_rank;  // # of key==T items (smallest idx first) selected

  // collect indices of key==T items (E is ~1 in practice)
#pragma unroll
  for (int q = 0; q < 4; q++) {
    if (key[q] == T) {
      int pos = atomicAdd(&eq_cnt, 1);
      if (pos < 1024) eq_idx[pos] = idx[q];
    }
  }
  __syncthreads();
  int E = min(eq_cnt, 1024);

  const unsigned KPOS = 0x80000000u;  // key of +0.0; corners need value > 0
  float term = 0.f;
#pragma unroll
  for (int q = 0; q < 4; q++) {
    bool corner = false;
    if (key[q] > KPOS) {
      if (key[q] > T) {
        corner = true;
      } else if (key[q] == T) {
        int r = 0;
        for (int j = 0; j < E; j++) r += (eq_idx[j] < idx[q]);
        corner = (r < need);
      }
    }
    if (corner) {
      float p = scores[(size_t)b * HW_ + idx[q]];
      term += fmaxf(logf(p), -100.f) - fmaxf(log1pf(-p), -100.f);
    }
  }
  for (int off = 32; off > 0; off >>= 1) term += __shfl_down(term, off);
  if ((tid & 63) == 0) wsum[tid >> 6] = term;
  __syncthreads();
  if (tid == 0) {
    double s = 0.0;
    for (int i = 0; i < 16; i++) s += (double)wsum[i];
    atomicAdd(acc, s);
  }
}

// K4: sum of clamp(log1p(-p), -100) over all pixels.
__global__ __launch_bounds__(256) void k_base(const float* __restrict__ scores,
                                              double* __restrict__ acc) {
  __shared__ float wsum[4];
  int tid = threadIdx.x;
  size_t gid = (size_t)blockIdx.x * 256 + tid;
  size_t stride = (size_t)gridDim.x * 256;
  float s = 0.f;
  const float4* s4 = (const float4*)scores;
  size_t n4 = (size_t)B_ * HW_ / 4;
  for (size_t i = gid; i < n4; i += stride) {
    float4 p = s4[i];
    s += fmaxf(log1pf(-p.x), -100.f);
    s += fmaxf(log1pf(-p.y), -100.f);
    s += fmaxf(log1pf(-p.z), -100.f);
    s += fmaxf(log1pf(-p.w), -100.f);
  }
  for (int off = 32; off > 0; off >>= 1) s += __shfl_down(s, off);
  if ((tid & 63) == 0) wsum[tid >> 6] = s;
  __syncthreads();
  if (tid == 0) {
    double t = 0.0;
    for (int i = 0; i < 4; i++) t += (double)wsum[i];
    atomicAdd(acc, t);
  }
}

__global__ void k_final(const double* __restrict__ acc, float* __restrict__ out) {
  out[0] = (float)(-acc[0] / (double)((size_t)B_ * HW_));
}

}  // namespace

extern "C" void kernel_launch(void* const* d_in, const int* in_sizes, int n_in,
                              void* d_out, int out_size, void* d_ws, size_t ws_size,
                              hipStream_t stream) {
  const float* scores = (const float*)d_in[0];
  const float* imgs = (const float*)d_in[1];
  float* out = (float*)d_out;

  char* ws = (char*)d_ws;
  double* acc = (double*)ws;                       // 8 B
  float* resp = (float*)(ws + 256);                // 16 MB
  float* cand_val = resp + (size_t)B_ * HW_;       // 16*4096 f32
  int* cand_idx = (int*)(cand_val + B_ * CAP_);    // 16*4096 i32

  hipMemsetAsync(d_ws, 0, 256, stream);  // zero acc each call
  k_resp<<<B_ * 256, 256, 0, stream>>>(imgs, resp);
  k_nms<<<B_ * 256, 256, 0, stream>>>(resp, cand_val, cand_idx);
  k_select<<<B_, 1024, 0, stream>>>(cand_val, cand_idx, scores, acc);
  k_base<<<1024, 256, 0, stream>>>(scores, acc);
  k_final<<<1, 1, 0, stream>>>(acc, out);
}

// Round 5
// 92.307 us; speedup vs baseline: 1.4875x; 1.4875x over previous
//
#include <hip/hip_runtime.h>
#include <math.h>
#include <limits.h>

namespace {

constexpr int B_ = 16;
constexpr int H_ = 512;
constexpr int W_ = 512;
constexpr int HW_ = H_ * W_;
constexpr int TS_ = 32;
constexpr int CAP_ = 4096;   // one slot per 8x8 sub-block per image (64*64)
constexpr int NSEL_ = 500;

// 7-tap gaussian, sigma=1, normalized (matches reference's np.exp/sum)
__device__ __constant__ float c_gw[7] = {
    0.004433048175243746f, 0.05400558262251428f, 0.24203622937611957f,
    0.3990502796522496f,  0.24203622937611957f, 0.05400558262251428f,
    0.004433048175243746f};

__device__ inline int reflect_i(int i, int n) {
  // jnp.pad mode='reflect': -1 -> 1, n -> n-2
  return i < 0 ? -i : (i > n - 1 ? 2 * (n - 1) - i : i);
}

// K1: imgs -> GFTT response map. One block = one 32x32 output tile.
__global__ __launch_bounds__(256) void k_resp(const float* __restrict__ imgs,
                                              float* __restrict__ resp) {
  int bid = blockIdx.x;
  int bx = bid & 15, by = (bid >> 4) & 15, b = bid >> 8;
  int r0 = by * TS_, c0 = bx * TS_;
  __shared__ float g_s[40][40];
  __shared__ float p_s[3][38][38];
  __shared__ float v_s[3][TS_][38];
  int tid = threadIdx.x;
  const float* img = imgs + (size_t)b * 3 * HW_;

  // grayscale with replicate clamp (matches sobel's edge padding)
  for (int l = tid; l < 40 * 40; l += 256) {
    int lr = l / 40, lc = l % 40;
    int gr = min(max(r0 - 4 + lr, 0), H_ - 1);
    int gc = min(max(c0 - 4 + lc, 0), W_ - 1);
    int o = gr * W_ + gc;
    g_s[lr][lc] = 0.299f * img[o] + 0.587f * img[HW_ + o] + 0.114f * img[2 * HW_ + o];
  }
  __syncthreads();

  // gradient products at rows/cols tile-3 .. tile+34, reflect-mapped into image
  for (int l = tid; l < 38 * 38; l += 256) {
    int lr = l / 38, lc = l % 38;
    int ar = reflect_i(r0 - 3 + lr, H_);
    int ac = reflect_i(c0 - 3 + lc, W_);
    int rm = max(ar - 1, 0)      - (r0 - 4);
    int rz = ar                  - (r0 - 4);
    int rp = min(ar + 1, H_ - 1) - (r0 - 4);
    int cm = max(ac - 1, 0)      - (c0 - 4);
    int cz = ac                  - (c0 - 4);
    int cp = min(ac + 1, W_ - 1) - (c0 - 4);
    float gnw = g_s[rm][cm], gn = g_s[rm][cz], gne = g_s[rm][cp];
    float gw_ = g_s[rz][cm],                   ge  = g_s[rz][cp];
    float gsw = g_s[rp][cm], gs = g_s[rp][cz], gse = g_s[rp][cp];
    float dx = ((gne - gnw) + 2.f * (ge - gw_) + (gse - gsw)) * 0.125f;
    float dy = ((gsw - gnw) + 2.f * (gs - gn) + (gse - gne)) * 0.125f;
    p_s[0][lr][lc] = dx * dx;
    p_s[1][lr][lc] = dy * dy;
    p_s[2][lr][lc] = dx * dy;
  }
  __syncthreads();

  // vertical 7-tap blur
  for (int l = tid; l < TS_ * 38; l += 256) {
    int lr = l / 38, lc = l % 38;
    float s0 = 0.f, s1 = 0.f, s2 = 0.f;
#pragma unroll
    for (int k = 0; k < 7; k++) {
      float w = c_gw[k];
      s0 += w * p_s[0][lr + k][lc];
      s1 += w * p_s[1][lr + k][lc];
      s2 += w * p_s[2][lr + k][lc];
    }
    v_s[0][lr][lc] = s0;
    v_s[1][lr][lc] = s1;
    v_s[2][lr][lc] = s2;
  }
  __syncthreads();

  // horizontal blur + min-eigenvalue response
  for (int l = tid; l < TS_ * TS_; l += 256) {
    int lr = l / TS_, lc = l % TS_;
    float b0 = 0.f, b1 = 0.f, b2 = 0.f;
#pragma unroll
    for (int k = 0; k < 7; k++) {
      float w = c_gw[k];
      b0 += w * v_s[0][lr][lc + k];
      b1 += w * v_s[1][lr][lc + k];
      b2 += w * v_s[2][lr][lc + k];
    }
    float tr = b0 + b1;
    float det = b0 * b1 - b2 * b2;
    float r = 0.5f * (tr - sqrtf(fabsf(tr * tr - 4.f * det) + 1e-12f));
    resp[((size_t)b * H_ + (r0 + lr)) * W_ + (c0 + lc)] = r;
  }
}

// K2: 5x5 NMS (pad=-inf) + per-8x8-block max into DETERMINISTIC slot
// cand[b*4096 + sub_global]. No atomics. Tie-break: min flat index.
__global__ __launch_bounds__(256) void k_nms(const float* __restrict__ resp,
                                             float* __restrict__ cand_val,
                                             int* __restrict__ cand_idx) {
  int bid = blockIdx.x;
  int bx = bid & 15, by = (bid >> 4) & 15, b = bid >> 8;
  int r0 = by * TS_, c0 = bx * TS_;
  __shared__ float r_s[36][36];
  __shared__ float c_s[32][32];
  int tid = threadIdx.x;
  const float* rb = resp + (size_t)b * HW_;
  for (int l = tid; l < 36 * 36; l += 256) {
    int lr = l / 36, lc = l % 36;
    int gr = r0 - 2 + lr, gc = c0 - 2 + lc;
    float v = -INFINITY;
    if (gr >= 0 && gr < H_ && gc >= 0 && gc < W_) v = rb[gr * W_ + gc];
    r_s[lr][lc] = v;
  }
  __syncthreads();
  for (int l = tid; l < 1024; l += 256) {
    int lr = l >> 5, lc = l & 31;
    float v = r_s[lr + 2][lc + 2];
    float m = -INFINITY;
#pragma unroll
    for (int u = 0; u < 5; u++)
#pragma unroll
      for (int w = 0; w < 5; w++) m = fmaxf(m, r_s[lr + u][lc + w]);
    c_s[lr][lc] = (v == m) ? v : 0.f;
  }
  __syncthreads();
  // one thread per 8x8 sub-block: max + min-index argmax, direct slot write
  if (tid < 16) {
    int sr = (tid >> 2) << 3, sc = (tid & 3) << 3;
    float m = 0.f;
    int mi = INT_MAX;
#pragma unroll
    for (int u = 0; u < 8; u++)
      for (int w = 0; w < 8; w++) {
        float v = c_s[sr + u][sc + w];
        if (v > m) { m = v; mi = (r0 + sr + u) * W_ + (c0 + sc + w); }
      }
    int subg = ((r0 + sr) >> 3) * 64 + ((c0 + sc) >> 3);
    bool pos = (m > 0.f);
    cand_val[b * CAP_ + subg] = pos ? m : -INFINITY;
    cand_idx[b * CAP_ + subg] = pos ? mi : INT_MAX;
  }
}

// K3: per-image top-500 via MSB-first RADIX SELECT (no sort). Items live in
// registers (4/thread). 4 passes x 8 bits: LDS histogram, then WAVE-0-ONLY
// parallel suffix-scan over the 256 bins (4 bins/lane + 6-step shfl_down) --
// no serial 256-iteration LDS chain. Finds the 500th-largest key T and
// `need` = slots left for key==T (idx asc, matching jax.lax.top_k tie order).
// Second nms2d is a provable no-op (equal values survive x==maxpool), so
// every selected positive item is a corner: add its BCE swap term directly.
__global__ __launch_bounds__(1024) void k_select(const float* __restrict__ cand_val,
                                                 const int* __restrict__ cand_idx,
                                                 const float* __restrict__ scores,
                                                 double* __restrict__ acc) {
  int b = blockIdx.x;
  __shared__ unsigned hist[256];
  __shared__ unsigned s_prefix;
  __shared__ int s_rank;
  __shared__ int eq_idx[1024];
  __shared__ int eq_cnt;
  __shared__ float wsum[16];
  int tid = threadIdx.x;

  unsigned key[4];
  int idx[4];
#pragma unroll
  for (int q = 0; q < 4; q++) {
    int l = tid + q * 1024;
    float v = cand_val[b * CAP_ + l];
    idx[q] = cand_idx[b * CAP_ + l];
    unsigned u = __float_as_uint(v);
    key[q] = (u & 0x80000000u) ? ~u : (u | 0x80000000u);  // order-preserving
  }
  if (tid == 0) { s_rank = NSEL_; s_prefix = 0; eq_cnt = 0; }

  for (int pass = 0; pass < 4; pass++) {
    int shift = 24 - 8 * pass;
    if (tid < 256) hist[tid] = 0;
    __syncthreads();
    unsigned pref = s_prefix;   // read-before-write: writes happen after next barrier
    int rank = s_rank;
#pragma unroll
    for (int q = 0; q < 4; q++) {
      bool match = (pass == 0) || ((key[q] >> (shift + 8)) == pref);
      if (match) atomicAdd(&hist[(key[q] >> shift) & 255u], 1u);
    }
    __syncthreads();
    if (tid < 64) {
      // lane t owns bins 4t..4t+3
      unsigned h0 = hist[tid * 4 + 0], h1 = hist[tid * 4 + 1];
      unsigned h2 = hist[tid * 4 + 2], h3 = hist[tid * 4 + 3];
      unsigned tot = h0 + h1 + h2 + h3;
      unsigned suf = tot;  // suffix sum over lanes >= tid
#pragma unroll
      for (int off = 1; off < 64; off <<= 1) {
        unsigned o = __shfl_down(suf, off);
        if (tid + off < 64) suf += o;
      }
      unsigned above3 = suf - tot;      // items in bins > 4t+3
      unsigned above2 = above3 + h3;
      unsigned above1 = above2 + h2;
      unsigned above0 = above1 + h1;
      unsigned r = (unsigned)rank;
      // exactly one (lane, bin) matches across the wave
      if (above0 < r && r <= above0 + h0) { s_rank = (int)(r - above0); s_prefix = (pref << 8) | (unsigned)(tid * 4 + 0); }
      if (above1 < r && r <= above1 + h1) { s_rank = (int)(r - above1); s_prefix = (pref << 8) | (unsigned)(tid * 4 + 1); }
      if (above2 < r && r <= above2 + h2) { s_rank = (int)(r - above2); s_prefix = (pref << 8) | (unsigned)(tid * 4 + 2); }
      if (above3 < r && r <= above3 + h3) { s_rank = (int)(r - above3); s_prefix = (pref << 8) | (unsigned)(tid * 4 + 3); }
    }
    __syncthreads();
  }
  unsigned T = s_prefix;
  int need = s_rank;  // # of key==T items (smallest idx first) selected

  // collect indices of key==T items (E is ~1 in practice)
#pragma unroll
  for (int q = 0; q < 4; q++) {
    if (key[q] == T) {
      int pos = atomicAdd(&eq_cnt, 1);
      if (pos < 1024) eq_idx[pos] = idx[q];
    }
  }
  __syncthreads();
  int E = min(eq_cnt, 1024);

  const unsigned KPOS = 0x80000000u;  // key of +0.0; corners need value > 0
  float term = 0.f;
#pragma unroll
  for (int q = 0; q < 4; q++) {
    bool corner = false;
    if (key[q] > KPOS) {
      if (key[q] > T) {
        corner = true;
      } else if (key[q] == T) {
        int r = 0;
        for (int j = 0; j < E; j++) r += (eq_idx[j] < idx[q]);
        corner = (r < need);
      }
    }
    if (corner) {
      float p = scores[(size_t)b * HW_ + idx[q]];
      term += fmaxf(logf(p), -100.f) - fmaxf(log1pf(-p), -100.f);
    }
  }
  for (int off = 32; off > 0; off >>= 1) term += __shfl_down(term, off);
  if ((tid & 63) == 0) wsum[tid >> 6] = term;
  __syncthreads();
  if (tid == 0) {
    double s = 0.0;
    for (int i = 0; i < 16; i++) s += (double)wsum[i];
    atomicAdd(acc, s);
  }
}

// K4: sum of clamp(log1p(-p), -100) over all pixels.
__global__ __launch_bounds__(256) void k_base(const float* __restrict__ scores,
                                              double* __restrict__ acc) {
  __shared__ float wsum[4];
  int tid = threadIdx.x;
  size_t gid = (size_t)blockIdx.x * 256 + tid;
  size_t stride = (size_t)gridDim.x * 256;
  float s = 0.f;
  const float4* s4 = (const float4*)scores;
  size_t n4 = (size_t)B_ * HW_ / 4;
  for (size_t i = gid; i < n4; i += stride) {
    float4 p = s4[i];
    s += fmaxf(log1pf(-p.x), -100.f);
    s += fmaxf(log1pf(-p.y), -100.f);
    s += fmaxf(log1pf(-p.z), -100.f);
    s += fmaxf(log1pf(-p.w), -100.f);
  }
  for (int off = 32; off > 0; off >>= 1) s += __shfl_down(s, off);
  if ((tid & 63) == 0) wsum[tid >> 6] = s;
  __syncthreads();
  if (tid == 0) {
    double t = 0.0;
    for (int i = 0; i < 4; i++) t += (double)wsum[i];
    atomicAdd(acc, t);
  }
}

__global__ void k_final(const double* __restrict__ acc, float* __restrict__ out) {
  out[0] = (float)(-acc[0] / (double)((size_t)B_ * HW_));
}

}  // namespace

extern "C" void kernel_launch(void* const* d_in, const int* in_sizes, int n_in,
                              void* d_out, int out_size, void* d_ws, size_t ws_size,
                              hipStream_t stream) {
  const float* scores = (const float*)d_in[0];
  const float* imgs = (const float*)d_in[1];
  float* out = (float*)d_out;

  char* ws = (char*)d_ws;
  double* acc = (double*)ws;                       // 8 B
  float* resp = (float*)(ws + 256);                // 16 MB
  float* cand_val = resp + (size_t)B_ * HW_;       // 16*4096 f32
  int* cand_idx = (int*)(cand_val + B_ * CAP_);    // 16*4096 i32

  hipMemsetAsync(d_ws, 0, 256, stream);  // zero acc each call
  k_resp<<<B_ * 256, 256, 0, stream>>>(imgs, resp);
  k_nms<<<B_ * 256, 256, 0, stream>>>(resp, cand_val, cand_idx);
  k_select<<<B_, 1024, 0, stream>>>(cand_val, cand_idx, scores, acc);
  k_base<<<1024, 256, 0, stream>>>(scores, acc);
  k_final<<<1, 1, 0, stream>>>(acc, out);
}

// Round 6
// 90.452 us; speedup vs baseline: 1.5180x; 1.0205x over previous
//
#include <hip/hip_runtime.h>
#include <math.h>
#include <limits.h>

namespace {

constexpr int B_ = 16;
constexpr int H_ = 512;
constexpr int W_ = 512;
constexpr int HW_ = H_ * W_;
constexpr int TS_ = 32;
constexpr int CAP_ = 4096;   // one slot per 8x8 sub-block per image (64*64)
constexpr int NSEL_ = 500;

typedef float f32x4 __attribute__((ext_vector_type(4)));
typedef float f32x2 __attribute__((ext_vector_type(2)));

__device__ inline f32x4 ld4(const float* p) { return *(const f32x4*)p; }
__device__ inline f32x2 ld2(const float* p) { return *(const f32x2*)p; }

// 7-tap gaussian, sigma=1, normalized (matches reference's np.exp/sum)
__device__ constexpr float GW[7] = {
    0.004433048175243746f, 0.05400558262251428f, 0.24203622937611957f,
    0.3990502796522496f,  0.24203622937611957f, 0.05400558262251428f,
    0.004433048175243746f};

__device__ inline int reflect_i(int i, int n) {
  // jnp.pad mode='reflect': -1 -> 1, n -> n-2
  return i < 0 ? -i : (i > n - 1 ? 2 * (n - 1) - i : i);
}

// K1: imgs -> GFTT response map. One block = one 32x32 output tile.
// Interior tiles (bx,by in [1,14]): float4 paths, no clamps.
// LDS rows padded to stride 40 floats (160B) for aligned b128 ops.
__global__ __launch_bounds__(256) void k_resp(const float* __restrict__ imgs,
                                              float* __restrict__ resp) {
  int bid = blockIdx.x;
  int bx = bid & 15, by = (bid >> 4) & 15, b = bid >> 8;
  int r0 = by * TS_, c0 = bx * TS_;
  __shared__ __align__(16) float g_s[40][40];
  __shared__ __align__(16) float p_s[3][38][40];
  __shared__ __align__(16) float v_s[3][32][40];
  int tid = threadIdx.x;
  const float* img = imgs + (size_t)b * 3 * HW_;
  bool interior = (bx >= 1 && bx <= 14 && by >= 1 && by <= 14);

  if (interior) {
    // Phase 1: grayscale, 40 rows x 10 float4 cols, all in-bounds & aligned
    for (int l = tid; l < 400; l += 256) {
      int row = l / 10, c4 = (l % 10) * 4;
      int o = (r0 - 4 + row) * W_ + (c0 - 4 + c4);
      f32x4 R = ld4(&img[o]);
      f32x4 G = ld4(&img[HW_ + o]);
      f32x4 Bl = ld4(&img[2 * HW_ + o]);
      f32x4 gray = 0.299f * R + 0.587f * G + 0.114f * Bl;
      *(f32x4*)&g_s[row][c4] = gray;
    }
    __syncthreads();
    // Phase 2: gradient products, 38 rows x 10 groups of 4 cols.
    // p(pr,pc) needs g rows pr..pr+2, cols pc..pc+2; group reads 6-wide window.
    for (int l = tid; l < 380; l += 256) {
      int pr = l / 10, c = (l % 10) * 4;
      f32x4 a0 = ld4(&g_s[pr][c]);     f32x2 e0 = ld2(&g_s[pr][c + 4]);
      f32x4 a1 = ld4(&g_s[pr + 1][c]); f32x2 e1 = ld2(&g_s[pr + 1][c + 4]);
      f32x4 a2 = ld4(&g_s[pr + 2][c]); f32x2 e2 = ld2(&g_s[pr + 2][c + 4]);
      float q0[6] = {a0[0], a0[1], a0[2], a0[3], e0[0], e0[1]};
      float q1[6] = {a1[0], a1[1], a1[2], a1[3], e1[0], e1[1]};
      float q2[6] = {a2[0], a2[1], a2[2], a2[3], e2[0], e2[1]};
      f32x4 P0, P1, P2;
#pragma unroll
      for (int j = 0; j < 4; j++) {
        float dxr = (q0[j + 2] - q0[j]) + 2.f * (q1[j + 2] - q1[j]) + (q2[j + 2] - q2[j]);
        float dyr = (q2[j] - q0[j]) + 2.f * (q2[j + 1] - q0[j + 1]) + (q2[j + 2] - q0[j + 2]);
        const float cc = 1.f / 64.f;  // sobel /8 twice, folded
        float t = dxr * cc, u = dyr * cc;
        P0[j] = t * dxr;
        P1[j] = u * dyr;
        P2[j] = t * dyr;
      }
      *(f32x4*)&p_s[0][pr][c] = P0;
      *(f32x4*)&p_s[1][pr][c] = P1;
      *(f32x4*)&p_s[2][pr][c] = P2;
    }
  } else {
    // border tiles: scalar path with replicate clamp + reflect (proven)
    for (int l = tid; l < 40 * 40; l += 256) {
      int lr = l / 40, lc = l % 40;
      int gr = min(max(r0 - 4 + lr, 0), H_ - 1);
      int gc = min(max(c0 - 4 + lc, 0), W_ - 1);
      int o = gr * W_ + gc;
      g_s[lr][lc] = 0.299f * img[o] + 0.587f * img[HW_ + o] + 0.114f * img[2 * HW_ + o];
    }
    __syncthreads();
    for (int l = tid; l < 38 * 38; l += 256) {
      int lr = l / 38, lc = l % 38;
      int ar = reflect_i(r0 - 3 + lr, H_);
      int ac = reflect_i(c0 - 3 + lc, W_);
      int rm = max(ar - 1, 0)      - (r0 - 4);
      int rz = ar                  - (r0 - 4);
      int rp = min(ar + 1, H_ - 1) - (r0 - 4);
      int cm = max(ac - 1, 0)      - (c0 - 4);
      int cz = ac                  - (c0 - 4);
      int cp = min(ac + 1, W_ - 1) - (c0 - 4);
      float gnw = g_s[rm][cm], gn = g_s[rm][cz], gne = g_s[rm][cp];
      float gw_ = g_s[rz][cm],                   ge  = g_s[rz][cp];
      float gsw = g_s[rp][cm], gs = g_s[rp][cz], gse = g_s[rp][cp];
      float dx = ((gne - gnw) + 2.f * (ge - gw_) + (gse - gsw)) * 0.125f;
      float dy = ((gsw - gnw) + 2.f * (gs - gn) + (gse - gne)) * 0.125f;
      p_s[0][lr][lc] = dx * dx;
      p_s[1][lr][lc] = dy * dy;
      p_s[2][lr][lc] = dx * dy;
    }
  }
  __syncthreads();

  // Phase 3: vertical 7-tap blur, 32 rows x 10 groups, b128 taps.
  // (group 9 cols 38,39 are pad garbage, never consumed downstream)
  for (int l = tid; l < 320; l += 256) {
    int vr = l / 10, c = (l % 10) * 4;
    f32x4 s0 = {0.f, 0.f, 0.f, 0.f};
    f32x4 s1 = {0.f, 0.f, 0.f, 0.f};
    f32x4 s2 = {0.f, 0.f, 0.f, 0.f};
#pragma unroll
    for (int k = 0; k < 7; k++) {
      float w = GW[k];
      s0 += w * ld4(&p_s[0][vr + k][c]);
      s1 += w * ld4(&p_s[1][vr + k][c]);
      s2 += w * ld4(&p_s[2][vr + k][c]);
    }
    *(f32x4*)&v_s[0][vr][c] = s0;
    *(f32x4*)&v_s[1][vr][c] = s1;
    *(f32x4*)&v_s[2][vr][c] = s2;
  }
  __syncthreads();

  // Phase 4: horizontal blur + response, 32 rows x 8 groups = 1 per thread.
  {
    int r = tid >> 3;
    int c = (tid & 7) << 2;
    float wa[3][10];
#pragma unroll
    for (int ch = 0; ch < 3; ch++) {
      f32x4 x = ld4(&v_s[ch][r][c]);
      f32x4 y = ld4(&v_s[ch][r][c + 4]);
      f32x2 z = ld2(&v_s[ch][r][c + 8]);
      wa[ch][0] = x[0]; wa[ch][1] = x[1]; wa[ch][2] = x[2]; wa[ch][3] = x[3];
      wa[ch][4] = y[0]; wa[ch][5] = y[1]; wa[ch][6] = y[2]; wa[ch][7] = y[3];
      wa[ch][8] = z[0]; wa[ch][9] = z[1];
    }
    f32x4 outv;
#pragma unroll
    for (int j = 0; j < 4; j++) {
      float b0 = 0.f, b1 = 0.f, b2 = 0.f;
#pragma unroll
      for (int t = 0; t < 7; t++) {
        b0 += GW[t] * wa[0][j + t];
        b1 += GW[t] * wa[1][j + t];
        b2 += GW[t] * wa[2][j + t];
      }
      float tr = b0 + b1;
      float det = b0 * b1 - b2 * b2;
      outv[j] = 0.5f * (tr - sqrtf(fabsf(tr * tr - 4.f * det) + 1e-12f));
    }
    *(f32x4*)&resp[((size_t)b * H_ + (r0 + r)) * W_ + (c0 + c)] = outv;
  }
}

// K2: 5x5 NMS (pad=-inf) + per-8x8-block max into DETERMINISTIC slot
// cand[b*4096 + sub_global]. No atomics. Tie-break: min flat index.
__global__ __launch_bounds__(256) void k_nms(const float* __restrict__ resp,
                                             float* __restrict__ cand_val,
                                             int* __restrict__ cand_idx) {
  int bid = blockIdx.x;
  int bx = bid & 15, by = (bid >> 4) & 15, b = bid >> 8;
  int r0 = by * TS_, c0 = bx * TS_;
  __shared__ float r_s[36][36];
  __shared__ float c_s[32][32];
  int tid = threadIdx.x;
  const float* rb = resp + (size_t)b * HW_;
  for (int l = tid; l < 36 * 36; l += 256) {
    int lr = l / 36, lc = l % 36;
    int gr = r0 - 2 + lr, gc = c0 - 2 + lc;
    float v = -INFINITY;
    if (gr >= 0 && gr < H_ && gc >= 0 && gc < W_) v = rb[gr * W_ + gc];
    r_s[lr][lc] = v;
  }
  __syncthreads();
  for (int l = tid; l < 1024; l += 256) {
    int lr = l >> 5, lc = l & 31;
    float v = r_s[lr + 2][lc + 2];
    float m = -INFINITY;
#pragma unroll
    for (int u = 0; u < 5; u++)
#pragma unroll
      for (int w = 0; w < 5; w++) m = fmaxf(m, r_s[lr + u][lc + w]);
    c_s[lr][lc] = (v == m) ? v : 0.f;
  }
  __syncthreads();
  // one thread per 8x8 sub-block: max + min-index argmax, direct slot write
  if (tid < 16) {
    int sr = (tid >> 2) << 3, sc = (tid & 3) << 3;
    float m = 0.f;
    int mi = INT_MAX;
#pragma unroll
    for (int u = 0; u < 8; u++)
      for (int w = 0; w < 8; w++) {
        float v = c_s[sr + u][sc + w];
        if (v > m) { m = v; mi = (r0 + sr + u) * W_ + (c0 + sc + w); }
      }
    int subg = ((r0 + sr) >> 3) * 64 + ((c0 + sc) >> 3);
    bool pos = (m > 0.f);
    cand_val[b * CAP_ + subg] = pos ? m : -INFINITY;
    cand_idx[b * CAP_ + subg] = pos ? mi : INT_MAX;
  }
}

// K3: per-image top-500 via MSB-first RADIX SELECT (no sort). Items live in
// registers (4/thread). 4 passes x 8 bits: LDS histogram, then WAVE-0-ONLY
// parallel suffix-scan over the 256 bins (4 bins/lane + 6-step shfl_down).
// Finds the 500th-largest key T and `need` = slots left for key==T (idx asc,
// matching jax.lax.top_k tie order). Second nms2d is a provable no-op (equal
// values survive x==maxpool), so every selected positive item is a corner:
// add its BCE swap term (log p - log1p(-p)) directly.
__global__ __launch_bounds__(1024) void k_select(const float* __restrict__ cand_val,
                                                 const int* __restrict__ cand_idx,
                                                 const float* __restrict__ scores,
                                                 double* __restrict__ acc) {
  int b = blockIdx.x;
  __shared__ unsigned hist[256];
  __shared__ unsigned s_prefix;
  __shared__ int s_rank;
  __shared__ int eq_idx[1024];
  __shared__ int eq_cnt;
  __shared__ float wsum[16];
  int tid = threadIdx.x;

  unsigned key[4];
  int idx[4];
#pragma unroll
  for (int q = 0; q < 4; q++) {
    int l = tid + q * 1024;
    float v = cand_val[b * CAP_ + l];
    idx[q] = cand_idx[b * CAP_ + l];
    unsigned u = __float_as_uint(v);
    key[q] = (u & 0x80000000u) ? ~u : (u | 0x80000000u);  // order-preserving
  }
  if (tid == 0) { s_rank = NSEL_; s_prefix = 0; eq_cnt = 0; }

  for (int pass = 0; pass < 4; pass++) {
    int shift = 24 - 8 * pass;
    if (tid < 256) hist[tid] = 0;
    __syncthreads();
    unsigned pref = s_prefix;   // read-before-write: writes happen after next barrier
    int rank = s_rank;
#pragma unroll
    for (int q = 0; q < 4; q++) {
      bool match = (pass == 0) || ((key[q] >> (shift + 8)) == pref);
      if (match) atomicAdd(&hist[(key[q] >> shift) & 255u], 1u);
    }
    __syncthreads();
    if (tid < 64) {
      // lane t owns bins 4t..4t+3
      unsigned h0 = hist[tid * 4 + 0], h1 = hist[tid * 4 + 1];
      unsigned h2 = hist[tid * 4 + 2], h3 = hist[tid * 4 + 3];
      unsigned tot = h0 + h1 + h2 + h3;
      unsigned suf = tot;  // suffix sum over lanes >= tid
#pragma unroll
      for (int off = 1; off < 64; off <<= 1) {
        unsigned o = __shfl_down(suf, off);
        if (tid + off < 64) suf += o;
      }
      unsigned above3 = suf - tot;      // items in bins > 4t+3
      unsigned above2 = above3 + h3;
      unsigned above1 = above2 + h2;
      unsigned above0 = above1 + h1;
      unsigned r = (unsigned)rank;
      // exactly one (lane, bin) matches across the wave
      if (above0 < r && r <= above0 + h0) { s_rank = (int)(r - above0); s_prefix = (pref << 8) | (unsigned)(tid * 4 + 0); }
      if (above1 < r && r <= above1 + h1) { s_rank = (int)(r - above1); s_prefix = (pref << 8) | (unsigned)(tid * 4 + 1); }
      if (above2 < r && r <= above2 + h2) { s_rank = (int)(r - above2); s_prefix = (pref << 8) | (unsigned)(tid * 4 + 2); }
      if (above3 < r && r <= above3 + h3) { s_rank = (int)(r - above3); s_prefix = (pref << 8) | (unsigned)(tid * 4 + 3); }
    }
    __syncthreads();
  }
  unsigned T = s_prefix;
  int need = s_rank;  // # of key==T items (smallest idx first) selected

  // collect indices of key==T items (E is ~1 in practice)
#pragma unroll
  for (int q = 0; q < 4; q++) {
    if (key[q] == T) {
      int pos = atomicAdd(&eq_cnt, 1);
      if (pos < 1024) eq_idx[pos] = idx[q];
    }
  }
  __syncthreads();
  int E = min(eq_cnt, 1024);

  const unsigned KPOS = 0x80000000u;  // key of +0.0; corners need value > 0
  float term = 0.f;
#pragma unroll
  for (int q = 0; q < 4; q++) {
    bool corner = false;
    if (key[q] > KPOS) {
      if (key[q] > T) {
        corner = true;
      } else if (key[q] == T) {
        int r = 0;
        for (int j = 0; j < E; j++) r += (eq_idx[j] < idx[q]);
        corner = (r < need);
      }
    }
    if (corner) {
      float p = scores[(size_t)b * HW_ + idx[q]];
      term += fmaxf(logf(p), -100.f) - fmaxf(log1pf(-p), -100.f);
    }
  }
  for (int off = 32; off > 0; off >>= 1) term += __shfl_down(term, off);
  if ((tid & 63) == 0) wsum[tid >> 6] = term;
  __syncthreads();
  if (tid == 0) {
    double s = 0.0;
    for (int i = 0; i < 16; i++) s += (double)wsum[i];
    atomicAdd(acc, s);
  }
}

// K4: sum of clamp(log1p(-p), -100) over all pixels.
__global__ __launch_bounds__(256) void k_base(const float* __restrict__ scores,
                                              double* __restrict__ acc) {
  __shared__ float wsum[4];
  int tid = threadIdx.x;
  size_t gid = (size_t)blockIdx.x * 256 + tid;
  size_t stride = (size_t)gridDim.x * 256;
  float s = 0.f;
  const float4* s4 = (const float4*)scores;
  size_t n4 = (size_t)B_ * HW_ / 4;
  for (size_t i = gid; i < n4; i += stride) {
    float4 p = s4[i];
    s += fmaxf(log1pf(-p.x), -100.f);
    s += fmaxf(log1pf(-p.y), -100.f);
    s += fmaxf(log1pf(-p.z), -100.f);
    s += fmaxf(log1pf(-p.w), -100.f);
  }
  for (int off = 32; off > 0; off >>= 1) s += __shfl_down(s, off);
  if ((tid & 63) == 0) wsum[tid >> 6] = s;
  __syncthreads();
  if (tid == 0) {
    double t = 0.0;
    for (int i = 0; i < 4; i++) t += (double)wsum[i];
    atomicAdd(acc, t);
  }
}

__global__ void k_final(const double* __restrict__ acc, float* __restrict__ out) {
  out[0] = (float)(-acc[0] / (double)((size_t)B_ * HW_));
}

}  // namespace

extern "C" void kernel_launch(void* const* d_in, const int* in_sizes, int n_in,
                              void* d_out, int out_size, void* d_ws, size_t ws_size,
                              hipStream_t stream) {
  const float* scores = (const float*)d_in[0];
  const float* imgs = (const float*)d_in[1];
  float* out = (float*)d_out;

  char* ws = (char*)d_ws;
  double* acc = (double*)ws;                       // 8 B
  float* resp = (float*)(ws + 256);                // 16 MB
  float* cand_val = resp + (size_t)B_ * HW_;       // 16*4096 f32
  int* cand_idx = (int*)(cand_val + B_ * CAP_);    // 16*4096 i32

  hipMemsetAsync(d_ws, 0, 256, stream);  // zero acc each call
  k_resp<<<B_ * 256, 256, 0, stream>>>(imgs, resp);
  k_nms<<<B_ * 256, 256, 0, stream>>>(resp, cand_val, cand_idx);
  k_select<<<B_, 1024, 0, stream>>>(cand_val, cand_idx, scores, acc);
  k_base<<<1024, 256, 0, stream>>>(scores, acc);
  k_final<<<1, 1, 0, stream>>>(acc, out);
}

// Round 7
// 86.144 us; speedup vs baseline: 1.5940x; 1.0500x over previous
//
#include <hip/hip_runtime.h>
#include <math.h>
#include <limits.h>

namespace {

constexpr int B_ = 16;
constexpr int H_ = 512;
constexpr int W_ = 512;
constexpr int HW_ = H_ * W_;
constexpr int TS_ = 32;
constexpr int CAP_ = 4096;   // one slot per 8x8 sub-block per image (64*64)
constexpr int NSEL_ = 500;
constexpr int NBASE_ = 1024;           // k_base blocks
constexpr int NPART_ = NBASE_ + B_;    // total partial slots

typedef float f32x4 __attribute__((ext_vector_type(4)));
typedef float f32x2 __attribute__((ext_vector_type(2)));

__device__ inline f32x4 ld4(const float* p) { return *(const f32x4*)p; }
__device__ inline f32x2 ld2(const float* p) { return *(const f32x2*)p; }

// 7-tap gaussian, sigma=1, normalized (matches reference's np.exp/sum)
__device__ constexpr float GW[7] = {
    0.004433048175243746f, 0.05400558262251428f, 0.24203622937611957f,
    0.3990502796522496f,  0.24203622937611957f, 0.05400558262251428f,
    0.004433048175243746f};

__device__ inline int reflect_i(int i, int n) {
  // jnp.pad mode='reflect': -1 -> 1, n -> n-2
  return i < 0 ? -i : (i > n - 1 ? 2 * (n - 1) - i : i);
}

// K1: imgs -> GFTT response map. One block = one 32x32 output tile.
// Interior tiles (bx,by in [1,14]): float4 paths, no clamps.
// LDS rows padded to stride 40 floats (160B) for aligned b128 ops.
__global__ __launch_bounds__(256) void k_resp(const float* __restrict__ imgs,
                                              float* __restrict__ resp) {
  int bid = blockIdx.x;
  int bx = bid & 15, by = (bid >> 4) & 15, b = bid >> 8;
  int r0 = by * TS_, c0 = bx * TS_;
  __shared__ __align__(16) float g_s[40][40];
  __shared__ __align__(16) float p_s[3][38][40];
  __shared__ __align__(16) float v_s[3][32][40];
  int tid = threadIdx.x;
  const float* img = imgs + (size_t)b * 3 * HW_;
  bool interior = (bx >= 1 && bx <= 14 && by >= 1 && by <= 14);

  if (interior) {
    // Phase 1: grayscale, 40 rows x 10 float4 cols, all in-bounds & aligned
    for (int l = tid; l < 400; l += 256) {
      int row = l / 10, c4 = (l % 10) * 4;
      int o = (r0 - 4 + row) * W_ + (c0 - 4 + c4);
      f32x4 R = ld4(&img[o]);
      f32x4 G = ld4(&img[HW_ + o]);
      f32x4 Bl = ld4(&img[2 * HW_ + o]);
      f32x4 gray = 0.299f * R + 0.587f * G + 0.114f * Bl;
      *(f32x4*)&g_s[row][c4] = gray;
    }
    __syncthreads();
    // Phase 2: gradient products, 38 rows x 10 groups of 4 cols.
    for (int l = tid; l < 380; l += 256) {
      int pr = l / 10, c = (l % 10) * 4;
      f32x4 a0 = ld4(&g_s[pr][c]);     f32x2 e0 = ld2(&g_s[pr][c + 4]);
      f32x4 a1 = ld4(&g_s[pr + 1][c]); f32x2 e1 = ld2(&g_s[pr + 1][c + 4]);
      f32x4 a2 = ld4(&g_s[pr + 2][c]); f32x2 e2 = ld2(&g_s[pr + 2][c + 4]);
      float q0[6] = {a0[0], a0[1], a0[2], a0[3], e0[0], e0[1]};
      float q1[6] = {a1[0], a1[1], a1[2], a1[3], e1[0], e1[1]};
      float q2[6] = {a2[0], a2[1], a2[2], a2[3], e2[0], e2[1]};
      f32x4 P0, P1, P2;
#pragma unroll
      for (int j = 0; j < 4; j++) {
        float dxr = (q0[j + 2] - q0[j]) + 2.f * (q1[j + 2] - q1[j]) + (q2[j + 2] - q2[j]);
        float dyr = (q2[j] - q0[j]) + 2.f * (q2[j + 1] - q0[j + 1]) + (q2[j + 2] - q0[j + 2]);
        const float cc = 1.f / 64.f;  // sobel /8 twice, folded
        float t = dxr * cc, u = dyr * cc;
        P0[j] = t * dxr;
        P1[j] = u * dyr;
        P2[j] = t * dyr;
      }
      *(f32x4*)&p_s[0][pr][c] = P0;
      *(f32x4*)&p_s[1][pr][c] = P1;
      *(f32x4*)&p_s[2][pr][c] = P2;
    }
  } else {
    // border tiles: scalar path with replicate clamp + reflect (proven)
    for (int l = tid; l < 40 * 40; l += 256) {
      int lr = l / 40, lc = l % 40;
      int gr = min(max(r0 - 4 + lr, 0), H_ - 1);
      int gc = min(max(c0 - 4 + lc, 0), W_ - 1);
      int o = gr * W_ + gc;
      g_s[lr][lc] = 0.299f * img[o] + 0.587f * img[HW_ + o] + 0.114f * img[2 * HW_ + o];
    }
    __syncthreads();
    for (int l = tid; l < 38 * 38; l += 256) {
      int lr = l / 38, lc = l % 38;
      int ar = reflect_i(r0 - 3 + lr, H_);
      int ac = reflect_i(c0 - 3 + lc, W_);
      int rm = max(ar - 1, 0)      - (r0 - 4);
      int rz = ar                  - (r0 - 4);
      int rp = min(ar + 1, H_ - 1) - (r0 - 4);
      int cm = max(ac - 1, 0)      - (c0 - 4);
      int cz = ac                  - (c0 - 4);
      int cp = min(ac + 1, W_ - 1) - (c0 - 4);
      float gnw = g_s[rm][cm], gn = g_s[rm][cz], gne = g_s[rm][cp];
      float gw_ = g_s[rz][cm],                   ge  = g_s[rz][cp];
      float gsw = g_s[rp][cm], gs = g_s[rp][cz], gse = g_s[rp][cp];
      float dx = ((gne - gnw) + 2.f * (ge - gw_) + (gse - gsw)) * 0.125f;
      float dy = ((gsw - gnw) + 2.f * (gs - gn) + (gse - gne)) * 0.125f;
      p_s[0][lr][lc] = dx * dx;
      p_s[1][lr][lc] = dy * dy;
      p_s[2][lr][lc] = dx * dy;
    }
  }
  __syncthreads();

  // Phase 3: vertical 7-tap blur, 32 rows x 10 groups, b128 taps.
  for (int l = tid; l < 320; l += 256) {
    int vr = l / 10, c = (l % 10) * 4;
    f32x4 s0 = {0.f, 0.f, 0.f, 0.f};
    f32x4 s1 = {0.f, 0.f, 0.f, 0.f};
    f32x4 s2 = {0.f, 0.f, 0.f, 0.f};
#pragma unroll
    for (int k = 0; k < 7; k++) {
      float w = GW[k];
      s0 += w * ld4(&p_s[0][vr + k][c]);
      s1 += w * ld4(&p_s[1][vr + k][c]);
      s2 += w * ld4(&p_s[2][vr + k][c]);
    }
    *(f32x4*)&v_s[0][vr][c] = s0;
    *(f32x4*)&v_s[1][vr][c] = s1;
    *(f32x4*)&v_s[2][vr][c] = s2;
  }
  __syncthreads();

  // Phase 4: horizontal blur + response, 32 rows x 8 groups = 1 per thread.
  {
    int r = tid >> 3;
    int c = (tid & 7) << 2;
    float wa[3][10];
#pragma unroll
    for (int ch = 0; ch < 3; ch++) {
      f32x4 x = ld4(&v_s[ch][r][c]);
      f32x4 y = ld4(&v_s[ch][r][c + 4]);
      f32x2 z = ld2(&v_s[ch][r][c + 8]);
      wa[ch][0] = x[0]; wa[ch][1] = x[1]; wa[ch][2] = x[2]; wa[ch][3] = x[3];
      wa[ch][4] = y[0]; wa[ch][5] = y[1]; wa[ch][6] = y[2]; wa[ch][7] = y[3];
      wa[ch][8] = z[0]; wa[ch][9] = z[1];
    }
    f32x4 outv;
#pragma unroll
    for (int j = 0; j < 4; j++) {
      float b0 = 0.f, b1 = 0.f, b2 = 0.f;
#pragma unroll
      for (int t = 0; t < 7; t++) {
        b0 += GW[t] * wa[0][j + t];
        b1 += GW[t] * wa[1][j + t];
        b2 += GW[t] * wa[2][j + t];
      }
      float tr = b0 + b1;
      float det = b0 * b1 - b2 * b2;
      outv[j] = 0.5f * (tr - sqrtf(fabsf(tr * tr - 4.f * det) + 1e-12f));
    }
    *(f32x4*)&resp[((size_t)b * H_ + (r0 + r)) * W_ + (c0 + c)] = outv;
  }
}

// K2: 5x5 NMS (pad=-inf) + per-8x8-block max into DETERMINISTIC slot
// cand[b*4096 + sub_global]. No atomics. Tie-break: min flat index.
__global__ __launch_bounds__(256) void k_nms(const float* __restrict__ resp,
                                             float* __restrict__ cand_val,
                                             int* __restrict__ cand_idx) {
  int bid = blockIdx.x;
  int bx = bid & 15, by = (bid >> 4) & 15, b = bid >> 8;
  int r0 = by * TS_, c0 = bx * TS_;
  __shared__ float r_s[36][36];
  __shared__ float c_s[32][32];
  int tid = threadIdx.x;
  const float* rb = resp + (size_t)b * HW_;
  for (int l = tid; l < 36 * 36; l += 256) {
    int lr = l / 36, lc = l % 36;
    int gr = r0 - 2 + lr, gc = c0 - 2 + lc;
    float v = -INFINITY;
    if (gr >= 0 && gr < H_ && gc >= 0 && gc < W_) v = rb[gr * W_ + gc];
    r_s[lr][lc] = v;
  }
  __syncthreads();
  for (int l = tid; l < 1024; l += 256) {
    int lr = l >> 5, lc = l & 31;
    float v = r_s[lr + 2][lc + 2];
    float m = -INFINITY;
#pragma unroll
    for (int u = 0; u < 5; u++)
#pragma unroll
      for (int w = 0; w < 5; w++) m = fmaxf(m, r_s[lr + u][lc + w]);
    c_s[lr][lc] = (v == m) ? v : 0.f;
  }
  __syncthreads();
  // one thread per 8x8 sub-block: max + min-index argmax, direct slot write
  if (tid < 16) {
    int sr = (tid >> 2) << 3, sc = (tid & 3) << 3;
    float m = 0.f;
    int mi = INT_MAX;
#pragma unroll
    for (int u = 0; u < 8; u++)
      for (int w = 0; w < 8; w++) {
        float v = c_s[sr + u][sc + w];
        if (v > m) { m = v; mi = (r0 + sr + u) * W_ + (c0 + sc + w); }
      }
    int subg = ((r0 + sr) >> 3) * 64 + ((c0 + sc) >> 3);
    bool pos = (m > 0.f);
    cand_val[b * CAP_ + subg] = pos ? m : -INFINITY;
    cand_idx[b * CAP_ + subg] = pos ? mi : INT_MAX;
  }
}

// K3: per-image top-500 via MSB-first RADIX SELECT (no sort). Items live in
// registers (4/thread). 4 passes x 8 bits: LDS histogram, then WAVE-0-ONLY
// parallel suffix-scan over the 256 bins (4 bins/lane + 6-step shfl_down).
// Finds the 500th-largest key T and `need` = slots left for key==T (idx asc,
// matching jax.lax.top_k tie order). Second nms2d is a provable no-op (equal
// values survive x==maxpool), so every selected positive item is a corner:
// add its BCE swap term (log p - log1p(-p)) to part[NBASE_+b] (no atomics).
__global__ __launch_bounds__(1024) void k_select(const float* __restrict__ cand_val,
                                                 const int* __restrict__ cand_idx,
                                                 const float* __restrict__ scores,
                                                 double* __restrict__ part) {
  int b = blockIdx.x;
  __shared__ unsigned hist[256];
  __shared__ unsigned s_prefix;
  __shared__ int s_rank;
  __shared__ int eq_idx[1024];
  __shared__ int eq_cnt;
  __shared__ float wsum[16];
  int tid = threadIdx.x;

  unsigned key[4];
  int idx[4];
#pragma unroll
  for (int q = 0; q < 4; q++) {
    int l = tid + q * 1024;
    float v = cand_val[b * CAP_ + l];
    idx[q] = cand_idx[b * CAP_ + l];
    unsigned u = __float_as_uint(v);
    key[q] = (u & 0x80000000u) ? ~u : (u | 0x80000000u);  // order-preserving
  }
  if (tid == 0) { s_rank = NSEL_; s_prefix = 0; eq_cnt = 0; }

  for (int pass = 0; pass < 4; pass++) {
    int shift = 24 - 8 * pass;
    if (tid < 256) hist[tid] = 0;
    __syncthreads();
    unsigned pref = s_prefix;   // read-before-write: writes happen after next barrier
    int rank = s_rank;
#pragma unroll
    for (int q = 0; q < 4; q++) {
      bool match = (pass == 0) || ((key[q] >> (shift + 8)) == pref);
      if (match) atomicAdd(&hist[(key[q] >> shift) & 255u], 1u);
    }
    __syncthreads();
    if (tid < 64) {
      // lane t owns bins 4t..4t+3
      unsigned h0 = hist[tid * 4 + 0], h1 = hist[tid * 4 + 1];
      unsigned h2 = hist[tid * 4 + 2], h3 = hist[tid * 4 + 3];
      unsigned tot = h0 + h1 + h2 + h3;
      unsigned suf = tot;  // suffix sum over lanes >= tid
#pragma unroll
      for (int off = 1; off < 64; off <<= 1) {
        unsigned o = __shfl_down(suf, off);
        if (tid + off < 64) suf += o;
      }
      unsigned above3 = suf - tot;      // items in bins > 4t+3
      unsigned above2 = above3 + h3;
      unsigned above1 = above2 + h2;
      unsigned above0 = above1 + h1;
      unsigned r = (unsigned)rank;
      // exactly one (lane, bin) matches across the wave
      if (above0 < r && r <= above0 + h0) { s_rank = (int)(r - above0); s_prefix = (pref << 8) | (unsigned)(tid * 4 + 0); }
      if (above1 < r && r <= above1 + h1) { s_rank = (int)(r - above1); s_prefix = (pref << 8) | (unsigned)(tid * 4 + 1); }
      if (above2 < r && r <= above2 + h2) { s_rank = (int)(r - above2); s_prefix = (pref << 8) | (unsigned)(tid * 4 + 2); }
      if (above3 < r && r <= above3 + h3) { s_rank = (int)(r - above3); s_prefix = (pref << 8) | (unsigned)(tid * 4 + 3); }
    }
    __syncthreads();
  }
  unsigned T = s_prefix;
  int need = s_rank;  // # of key==T items (smallest idx first) selected

  // collect indices of key==T items (E is ~1 in practice)
#pragma unroll
  for (int q = 0; q < 4; q++) {
    if (key[q] == T) {
      int pos = atomicAdd(&eq_cnt, 1);
      if (pos < 1024) eq_idx[pos] = idx[q];
    }
  }
  __syncthreads();
  int E = min(eq_cnt, 1024);

  const unsigned KPOS = 0x80000000u;  // key of +0.0; corners need value > 0
  float term = 0.f;
#pragma unroll
  for (int q = 0; q < 4; q++) {
    bool corner = false;
    if (key[q] > KPOS) {
      if (key[q] > T) {
        corner = true;
      } else if (key[q] == T) {
        int r = 0;
        for (int j = 0; j < E; j++) r += (eq_idx[j] < idx[q]);
        corner = (r < need);
      }
    }
    if (corner) {
      float p = scores[(size_t)b * HW_ + idx[q]];
      term += fmaxf(logf(p), -100.f) - fmaxf(log1pf(-p), -100.f);
    }
  }
  for (int off = 32; off > 0; off >>= 1) term += __shfl_down(term, off);
  if ((tid & 63) == 0) wsum[tid >> 6] = term;
  __syncthreads();
  if (tid == 0) {
    double s = 0.0;
    for (int i = 0; i < 16; i++) s += (double)wsum[i];
    part[NBASE_ + b] = s;   // deterministic slot, overwritten every call
  }
}

// K4: sum of clamp(log1p(-p), -100) over all pixels -> part[blockIdx.x].
__global__ __launch_bounds__(256) void k_base(const float* __restrict__ scores,
                                              double* __restrict__ part) {
  __shared__ float wsum[4];
  int tid = threadIdx.x;
  size_t gid = (size_t)blockIdx.x * 256 + tid;
  size_t stride = (size_t)gridDim.x * 256;
  float s = 0.f;
  const float4* s4 = (const float4*)scores;
  size_t n4 = (size_t)B_ * HW_ / 4;
  for (size_t i = gid; i < n4; i += stride) {
    float4 p = s4[i];
    s += fmaxf(log1pf(-p.x), -100.f);
    s += fmaxf(log1pf(-p.y), -100.f);
    s += fmaxf(log1pf(-p.z), -100.f);
    s += fmaxf(log1pf(-p.w), -100.f);
  }
  for (int off = 32; off > 0; off >>= 1) s += __shfl_down(s, off);
  if ((tid & 63) == 0) wsum[tid >> 6] = s;
  __syncthreads();
  if (tid == 0) {
    double t = 0.0;
    for (int i = 0; i < 4; i++) t += (double)wsum[i];
    part[blockIdx.x] = t;   // deterministic slot, overwritten every call
  }
}

// K5: reduce the NPART_ partial doubles -> loss. One block, 256 threads.
__global__ __launch_bounds__(256) void k_final(const double* __restrict__ part,
                                               float* __restrict__ out) {
  __shared__ double wsum[4];
  int tid = threadIdx.x;
  double s = 0.0;
  for (int i = tid; i < NPART_; i += 256) s += part[i];
  for (int off = 32; off > 0; off >>= 1) s += __shfl_down(s, off);
  if ((tid & 63) == 0) wsum[tid >> 6] = s;
  __syncthreads();
  if (tid == 0) {
    double t = wsum[0] + wsum[1] + wsum[2] + wsum[3];
    out[0] = (float)(-t / (double)((size_t)B_ * HW_));
  }
}

}  // namespace

extern "C" void kernel_launch(void* const* d_in, const int* in_sizes, int n_in,
                              void* d_out, int out_size, void* d_ws, size_t ws_size,
                              hipStream_t stream) {
  const float* scores = (const float*)d_in[0];
  const float* imgs = (const float*)d_in[1];
  float* out = (float*)d_out;

  char* ws = (char*)d_ws;
  double* part = (double*)ws;                      // NPART_ doubles (8320 B)
  float* resp = (float*)(ws + 16384);              // 16 MB, 16KB-aligned
  float* cand_val = resp + (size_t)B_ * HW_;       // 16*4096 f32
  int* cand_idx = (int*)(cand_val + B_ * CAP_);    // 16*4096 i32

  k_resp<<<B_ * 256, 256, 0, stream>>>(imgs, resp);
  k_nms<<<B_ * 256, 256, 0, stream>>>(resp, cand_val, cand_idx);
  k_select<<<B_, 1024, 0, stream>>>(cand_val, cand_idx, scores, part);
  k_base<<<NBASE_, 256, 0, stream>>>(scores, part);
  k_final<<<1, 256, 0, stream>>>(part, out);
}